// Round 2
// baseline (479.215 us; speedup 1.0000x reference)
//
#include <hip/hip_runtime.h>
#include <hip/hip_bf16.h>

// Problem shape: img (1, X=192, Y=192, Z=48, C=64) fp32, rois (1, R=64, 6) int32
// (x, y, z, w, h, d), pool_size P=7, out (1, R, P, P, C) fp32.
#define XD 192
#define YD 192
#define ZD 48
#define CD 64
#define PP 7
#define NCELLS (64 * PP * PP)   // 3136 output (r,px,py) cells
#define THREADS 256

// One thread per (cell, 4-channel group): 3136 cells x 16 float4 = 50176 threads.
// Each thread: 4 gathered float4 loads (16 B, dwordx4) + 1 float4 store.
__global__ __launch_bounds__(THREADS) void roi_pool_kernel(
    const float4* __restrict__ img4,
    const int* __restrict__ rois,
    float4* __restrict__ out4) {
  const int tid = blockIdx.x * THREADS + threadIdx.x;
  const int q = tid & 15;        // which float4 within the 64-channel vector
  int cell = tid >> 4;           // r * 49 + px * 7 + py

  const int py = cell % PP;
  int t = cell / PP;
  const int px = t % PP;
  const int r = t / PP;

  const int* roi = rois + r * 6;
  const int x = roi[0];
  const int y = roi[1];
  const int z = roi[2];
  const int w = roi[3];
  const int h = roi[4];

  // Match reference math exactly (fp32, same op order):
  const float sxv = (float)px * ((float)w / 7.0f);
  const float syv = (float)py * ((float)h / 7.0f);
  const int x0 = (int)floorf(sxv);
  const int y0 = (int)floorf(syv);
  const float fx = sxv - (float)x0;
  const float fy = syv - (float)y0;

  const int x0c = min(max(x0, 0), w - 1);
  const int x1c = min(max(x0 + 1, 0), w - 1);
  const int y0c = min(max(y0, 0), h - 1);
  const int y1c = min(max(y0 + 1, 0), h - 1);
  const int x0a = min(max(x + x0c, 0), XD - 1);
  const int x1a = min(max(x + x1c, 0), XD - 1);
  const int y0a = min(max(y + y0c, 0), YD - 1);
  const int y1a = min(max(y + y1c, 0), YD - 1);
  const int zc  = min(max(z, 0), ZD - 1);

  // pixel index (in units of 64-ch vectors), then float4 units: *16 + q
  const int p00 = (x0a * YD + y0a) * ZD + zc;
  const int p10 = (x1a * YD + y0a) * ZD + zc;
  const int p01 = (x0a * YD + y1a) * ZD + zc;
  const int p11 = (x1a * YD + y1a) * ZD + zc;

  const float4 v00 = img4[p00 * 16 + q];
  const float4 v10 = img4[p10 * 16 + q];
  const float4 v01 = img4[p01 * 16 + q];
  const float4 v11 = img4[p11 * 16 + q];

  const float w00 = (1.0f - fx) * (1.0f - fy);
  const float w10 = fx * (1.0f - fy);
  const float w01 = (1.0f - fx) * fy;
  const float w11 = fx * fy;

  float4 res;
  res.x = v00.x * w00 + v10.x * w10 + v01.x * w01 + v11.x * w11;
  res.y = v00.y * w00 + v10.y * w10 + v01.y * w01 + v11.y * w11;
  res.z = v00.z * w00 + v10.z * w10 + v01.z * w01 + v11.z * w11;
  res.w = v00.w * w00 + v10.w * w10 + v01.w * w01 + v11.w * w11;

  out4[cell * 16 + q] = res;
}

extern "C" void kernel_launch(void* const* d_in, const int* in_sizes, int n_in,
                              void* d_out, int out_size, void* d_ws, size_t ws_size,
                              hipStream_t stream) {
  const float4* img4 = (const float4*)d_in[0];
  const int*    rois = (const int*)d_in[1];
  float4* out4 = (float4*)d_out;

  const int nthreads = NCELLS * 16;                 // 50176
  const int nblocks = (nthreads + THREADS - 1) / THREADS;  // 196
  roi_pool_kernel<<<nblocks, THREADS, 0, stream>>>(img4, rois, out4);
}